// Round 6
// baseline (285.906 us; speedup 1.0000x reference)
//
#include <hip/hip_runtime.h>

#define NF 64  // feature dim for both GCN layers

__device__ __forceinline__ float rlf(float v, int l) {
    return __int_as_float(__builtin_amdgcn_readlane(__float_as_int(v), l));
}
__device__ __forceinline__ int rfl(int v) { return __builtin_amdgcn_readfirstlane(v); }

// ---------------- CSR build ----------------

__global__ void count_deg(const int* __restrict__ dst, int* __restrict__ cnt, int E) {
    int e = blockIdx.x * blockDim.x + threadIdx.x;
    if (e < E) atomicAdd(&cnt[dst[e]], 1);
}

// pass 1: block-local exclusive scan (1024 elems/block) + block sums
__global__ __launch_bounds__(1024) void scan_blk(const int* __restrict__ cnt,
                                                 int* __restrict__ rowptr,
                                                 int* __restrict__ bsum, int n) {
    __shared__ int wsum[16];
    __shared__ int wexcl[16];
    int tid = threadIdx.x, lane = tid & 63, w = tid >> 6;
    int i = blockIdx.x * 1024 + tid;
    int v = (i < n) ? cnt[i] : 0;
    int inc = v;
#pragma unroll
    for (int d = 1; d < 64; d <<= 1) {
        int t = __shfl_up(inc, d);
        if (lane >= d) inc += t;
    }
    if (lane == 63) wsum[w] = inc;
    __syncthreads();
    if (w == 0 && lane < 16) {
        int s = wsum[lane];
        int e2 = s;
#pragma unroll
        for (int d = 1; d < 16; d <<= 1) {
            int t = __shfl_up(e2, d);
            if (lane >= d) e2 += t;
        }
        wexcl[lane] = e2 - s;
    }
    __syncthreads();
    if (i < n) rowptr[i] = wexcl[w] + inc - v;
    if (tid == 1023) bsum[blockIdx.x] = wexcl[15] + wsum[15];
}

// pass 2: single-block exclusive scan of block sums (nb <= 1024)
__global__ __launch_bounds__(1024) void scan_part(int* __restrict__ bsum, int nb) {
    __shared__ int wsum[16];
    __shared__ int wexcl[16];
    int tid = threadIdx.x, lane = tid & 63, w = tid >> 6;
    int v = (tid < nb) ? bsum[tid] : 0;
    int inc = v;
#pragma unroll
    for (int d = 1; d < 64; d <<= 1) {
        int t = __shfl_up(inc, d);
        if (lane >= d) inc += t;
    }
    if (lane == 63) wsum[w] = inc;
    __syncthreads();
    if (w == 0 && lane < 16) {
        int s = wsum[lane];
        int e2 = s;
#pragma unroll
        for (int d = 1; d < 16; d <<= 1) {
            int t = __shfl_up(e2, d);
            if (lane >= d) e2 += t;
        }
        wexcl[lane] = e2 - s;
    }
    __syncthreads();
    if (tid < nb) bsum[tid] = wexcl[w] + inc - v;
}

// pass 3: add block offsets; write rowptr[n]; fused dinv + fill init
__global__ void scan_add(int* __restrict__ rowptr, const int* __restrict__ bsum,
                         const int* __restrict__ cnt, float* __restrict__ dinv,
                         int* __restrict__ fill, int n) {
    int i = blockIdx.x * blockDim.x + threadIdx.x;
    if (i < n) {
        int c = cnt[i];
        int r = rowptr[i] + bsum[i >> 10];
        rowptr[i] = r;
        if (i == n - 1) rowptr[n] = r + c;
        dinv[i] = rsqrtf((float)(c + 1));  // +1 self-loop
        fill[i] = 0;
    }
}

// srcs-only CSR payload (weight re-derived from dinv in the gather)
__global__ void fill_csr(const int* __restrict__ src, const int* __restrict__ dst,
                         const int* __restrict__ rowptr, int* __restrict__ fill,
                         int* __restrict__ srcs, int E) {
    int e = blockIdx.x * blockDim.x + threadIdx.x;
    if (e >= E) return;
    int d = dst[e];
    int pos = rowptr[d] + atomicAdd(&fill[d], 1);
    srcs[pos] = src[e];
}

// ---------------- fused gather + transform (+ decoder), 2 nodes/wave ----------------
// out = relu( agg(xin) @ W + b );  agg and transform commute (both linear).
// Wave handles node pair (i0,i1): two independent gather streams double the
// loads in flight; all FMA reduction chains split 4-way for ILP.
// Gather layout: 16 lanes x float4 per row -> one dwordx4 wave-load = 4 edges.

template <bool DEC>
__global__ __launch_bounds__(256) void gcn_layer(
    const int* __restrict__ srcs, const int* __restrict__ rowptr,
    const float* __restrict__ dinv, const float* __restrict__ xin,
    const float* __restrict__ W, const float* __restrict__ bias,
    float* __restrict__ xout,
    const float* __restrict__ Wd1, const float* __restrict__ bd1,
    const float* __restrict__ Wd2, const float* __restrict__ bd2,
    float* __restrict__ pred, int n)
{
    __shared__ float Wd1l[64][32];  // [k][j]: 32 distinct banks, 2 lanes/addr = free
    __shared__ float bd1l[32];
    __shared__ float w2l[32];
    int tid = threadIdx.x;
    int lane = tid & 63;
    if (DEC) {
        for (int i = tid; i < 2048; i += 256) Wd1l[i >> 5][i & 31] = Wd1[i];
        if (tid < 32) { bd1l[tid] = bd1[tid]; w2l[tid] = Wd2[tid]; }
    }
    __syncthreads();

    // W column `lane` in registers (uses the 128-VGPR bucket headroom)
    float wcol[64];
#pragma unroll
    for (int k = 0; k < 64; ++k) wcol[k] = W[k * NF + lane];
    float bv = bias[lane];
    float bd2v = DEC ? bd2[0] : 0.0f;

    int q = lane >> 4;          // quarter: which of 4 edges this lane serves
    int fl = (lane & 15) * 4;   // feature base for this lane

    int widx = blockIdx.x * 4 + (tid >> 6);
    int nw = gridDim.x * 4;
    int npair = (n + 1) >> 1;
    for (int t = widx; t < npair; t += nw) {
        int i0 = t * 2, i1 = i0 + 1;
        bool has1 = i1 < n;
        float d0 = dinv[i0];
        float d1 = has1 ? dinv[i1] : 0.0f;
        int jb0 = rfl(rowptr[i0]);
        int je0 = rfl(rowptr[i0 + 1]);
        int je1 = has1 ? rfl(rowptr[i0 + 2]) : je0;
        int jb1 = je0;  // i1's edges start where i0's end (adjacent rows)

        // self-loop messages (only quarter 0 carries weight; others add 0)
        float4 sv0 = *reinterpret_cast<const float4*>(xin + (size_t)i0 * NF + fl);
        float4 sv1 = *reinterpret_cast<const float4*>(xin + (size_t)(has1 ? i1 : i0) * NF + fl);
        float ws0 = (q == 0) ? d0 * d0 : 0.0f;
        float ws1 = (q == 0) ? d1 * d1 : 0.0f;  // d1=0 if !has1
        float a0[4] = {sv0.x * ws0, sv0.y * ws0, sv0.z * ws0, sv0.w * ws0};
        float a1[4] = {sv1.x * ws1, sv1.y * ws1, sv1.z * ws1, sv1.w * ws1};

        int base0 = jb0, base1 = jb1;
        int rem0 = je0 - jb0, rem1 = je1 - jb1;
        while (rem0 > 0 || rem1 > 0) {
            int c0 = min(64, rem0), c1 = min(64, rem1);  // may be <=0
            int s0 = 0, s1 = 0;
            float w0 = 0.0f, w1 = 0.0f;
            if (lane < c0) { s0 = srcs[base0 + lane]; w0 = dinv[s0] * d0; }  // dinv: 200KB, L2-hot
            if (lane < c1) { s1 = srcs[base1 + lane]; w1 = dinv[s1] * d1; }
            int cmax = max(c0, c1);
            for (int e = 0; e < cmax; e += 4) {
                int sl = e + q;  // <= 63
                int   sA = __shfl(s0, sl);
                float wA = __shfl(w0, sl);   // 0 for exhausted/tail lanes
                int   sB = __shfl(s1, sl);
                float wB = __shfl(w1, sl);
                float4 vA = *reinterpret_cast<const float4*>(xin + (size_t)sA * NF + fl);
                float4 vB = *reinterpret_cast<const float4*>(xin + (size_t)sB * NF + fl);
                a0[0] = fmaf(vA.x, wA, a0[0]);
                a0[1] = fmaf(vA.y, wA, a0[1]);
                a0[2] = fmaf(vA.z, wA, a0[2]);
                a0[3] = fmaf(vA.w, wA, a0[3]);
                a1[0] = fmaf(vB.x, wB, a1[0]);
                a1[1] = fmaf(vB.y, wB, a1[1]);
                a1[2] = fmaf(vB.z, wB, a1[2]);
                a1[3] = fmaf(vB.w, wB, a1[3]);
            }
            base0 += 64; base1 += 64; rem0 -= 64; rem1 -= 64;
        }
        // reduce across quarters: all lanes end with full feature sums
#pragma unroll
        for (int j2 = 0; j2 < 4; ++j2) {
            a0[j2] += __shfl_xor(a0[j2], 16);
            a0[j2] += __shfl_xor(a0[j2], 32);
            a1[j2] += __shfl_xor(a1[j2], 16);
            a1[j2] += __shfl_xor(a1[j2], 32);
        }

        // transform: o[lane] = relu( sum_k a_k * W[k][lane] + b ), 8 chains of 16
        // feature k=4m+j lives in a[j] of lane m
        float t00 = 0, t01 = 0, t02 = 0, t03 = 0;
        float t10 = 0, t11 = 0, t12 = 0, t13 = 0;
#pragma unroll
        for (int m = 0; m < 16; ++m) {
            float wc0 = wcol[4 * m], wc1 = wcol[4 * m + 1];
            float wc2 = wcol[4 * m + 2], wc3 = wcol[4 * m + 3];
            t00 = fmaf(rlf(a0[0], m), wc0, t00);
            t01 = fmaf(rlf(a0[1], m), wc1, t01);
            t02 = fmaf(rlf(a0[2], m), wc2, t02);
            t03 = fmaf(rlf(a0[3], m), wc3, t03);
            t10 = fmaf(rlf(a1[0], m), wc0, t10);
            t11 = fmaf(rlf(a1[1], m), wc1, t11);
            t12 = fmaf(rlf(a1[2], m), wc2, t12);
            t13 = fmaf(rlf(a1[3], m), wc3, t13);
        }
        float o0 = fmaxf(((t00 + t01) + (t02 + t03)) + bv, 0.0f);
        float o1 = fmaxf(((t10 + t11) + (t12 + t13)) + bv, 0.0f);

        if (!DEC) {
            xout[(size_t)i0 * NF + lane] = o0;
            if (has1) xout[(size_t)i1 * NF + lane] = o1;
        } else {
            int j = lane & 31;
            float sA = 0, sB = 0, sC = 0, sD = 0;  // 2-way split per node
#pragma unroll
            for (int k = 0; k < 64; k += 2) {
                float wd0 = Wd1l[k][j], wd1 = Wd1l[k + 1][j];
                sA = fmaf(rlf(o0, k), wd0, sA);
                sB = fmaf(rlf(o0, k + 1), wd1, sB);
                sC = fmaf(rlf(o1, k), wd0, sC);
                sD = fmaf(rlf(o1, k + 1), wd1, sD);
            }
            float h0 = fmaxf(sA + sB + bd1l[j], 0.0f);
            float h1 = fmaxf(sC + sD + bd1l[j], 0.0f);
            float p0 = h0 * w2l[j], p1 = h1 * w2l[j];
#pragma unroll
            for (int m = 16; m >= 1; m >>= 1) {
                p0 += __shfl_xor(p0, m);
                p1 += __shfl_xor(p1, m);
            }
            if (lane == 0) {
                pred[i0] = p0 + bd2v;
                if (has1) pred[i1] = p1 + bd2v;
            }
        }
    }
}

// ---------------- host launcher ----------------

extern "C" void kernel_launch(void* const* d_in, const int* in_sizes, int n_in,
                              void* d_out, int out_size, void* d_ws, size_t ws_size,
                              hipStream_t stream) {
    const float* x   = (const float*)d_in[0];
    const int*   ei  = (const int*)d_in[1];
    const float* W1  = (const float*)d_in[2];
    const float* b1  = (const float*)d_in[3];
    const float* W2  = (const float*)d_in[4];
    const float* b2  = (const float*)d_in[5];
    const float* Wd1 = (const float*)d_in[6];
    const float* bd1 = (const float*)d_in[7];
    const float* Wd2 = (const float*)d_in[8];
    const float* bd2 = (const float*)d_in[9];
    float* pred = (float*)d_out;

    const int N = in_sizes[0] / NF;
    const int E = in_sizes[1] / 2;
    const int* src = ei;
    const int* dst = ei + E;

    // workspace layout
    char* ws = (char*)d_ws;
    size_t off = 0;
    int*   cnt    = (int*)(ws + off);   off += (size_t)4 * N;
    int*   rowptr = (int*)(ws + off);   off += (size_t)4 * (N + 1);
    int*   fill   = (int*)(ws + off);   off += (size_t)4 * N;
    float* dinv   = (float*)(ws + off); off += (size_t)4 * N;
    int*   bsum   = (int*)(ws + off);   off += (size_t)4 * 1024;
    off = (off + 15) & ~(size_t)15;
    int*   srcs   = (int*)(ws + off);   off += (size_t)4 * E;
    off = (off + 15) & ~(size_t)15;
    float* h1     = (float*)(ws + off);

    const int B = 256;
    const int eb = (E + B - 1) / B;
    const int nb = (N + B - 1) / B;
    const int nb1024 = (N + 1023) / 1024;

    // CSR build (by dst) + dinv
    hipMemsetAsync(cnt, 0, (size_t)4 * N, stream);
    count_deg<<<eb, B, 0, stream>>>(dst, cnt, E);
    scan_blk<<<nb1024, 1024, 0, stream>>>(cnt, rowptr, bsum, N);
    scan_part<<<1, 1024, 0, stream>>>(bsum, nb1024);
    scan_add<<<nb, B, 0, stream>>>(rowptr, bsum, cnt, dinv, fill, N);
    fill_csr<<<eb, B, 0, stream>>>(src, dst, rowptr, fill, srcs, E);

    const int gb = 1024;  // 4 blocks/CU resident (128-VGPR bucket), grid-stride

    // layer 1: h1 = relu( agg(x) @ W1 + b1 )
    gcn_layer<false><<<gb, B, 0, stream>>>(srcs, rowptr, dinv, x, W1, b1, h1,
                                           Wd1, bd1, Wd2, bd2, pred, N);
    // layer 2 + decoder
    gcn_layer<true><<<gb, B, 0, stream>>>(srcs, rowptr, dinv, h1, W2, b2, h1,
                                          Wd1, bd1, Wd2, bd2, pred, N);
}